// Round 1
// baseline (688.165 us; speedup 1.0000x reference)
//
#include <hip/hip_runtime.h>
#include <math.h>

#define BB 32
#define LL 8192
#define DD 512
#define CHUNKS 32                       // blocks per batch in pass 1
#define ROWS_PER_BLOCK (LL / CHUNKS)    // 256 rows/block, 64 rows/wave
#define NCHUNK CHUNKS                   // partials per batch (1 per block)
#define PSTRIDE (2 + DD)                // [m, s, ctx[512]]

// ws float layout
#define TV_OFF ((size_t)BB * NCHUNK * PSTRIDE)   // partials end: 32*32*514 = 526336
#define MS_OFF (TV_OFF + (size_t)BB * 1024)      // tanh vectors: B*1024
// ms: B*2 floats (m_b, 1/s_b). Total ws use ~2.24 MB.

// ---------------- Pass 1: scores + online-softmax partial context ----------------
__global__ __launch_bounds__(256) void la_pass1(const float* __restrict__ h,
                                                const float* __restrict__ s,
                                                float* __restrict__ eOut,
                                                float* __restrict__ ws) {
    const int b     = blockIdx.x / CHUNKS;
    const int chunk = blockIdx.x % CHUNKS;
    const int tid   = threadIdx.x;
    const int wave  = tid >> 6;
    const int lane  = tid & 63;

    // preload s_i fragments: lane owns cols [4*lane..4*lane+3] and [256+4*lane..]
    const float4* s4 = (const float4*)(s + (size_t)b * DD);
    const float4 sv0 = s4[lane];
    const float4 sv1 = s4[lane + 64];

    float m = -INFINITY, ssum = 0.0f;
    float4 c0 = {0.f,0.f,0.f,0.f}, c1 = {0.f,0.f,0.f,0.f};

    const int l0 = chunk * ROWS_PER_BLOCK;
    const float4* hbase = (const float4*)(h + (size_t)b * LL * DD);

    for (int r = wave; r < ROWS_PER_BLOCK; r += 4) {
        const int l = l0 + r;
        const float4* hrow = hbase + (size_t)l * (DD / 4);
        float4 h0 = hrow[lane];
        float4 h1 = hrow[lane + 64];
        float dot = h0.x*sv0.x + h0.y*sv0.y + h0.z*sv0.z + h0.w*sv0.w
                  + h1.x*sv1.x + h1.y*sv1.y + h1.z*sv1.z + h1.w*sv1.w;
        #pragma unroll
        for (int off = 32; off > 0; off >>= 1) dot += __shfl_xor(dot, off, 64);
        if (lane == 0) eOut[(size_t)b * LL + l] = dot;   // raw score, normalized in pass 3
        // online softmax update
        float mn   = fmaxf(m, dot);
        float corr = __expf(m - mn);     // 0 on first iter (m = -inf)
        float p    = __expf(dot - mn);
        ssum = ssum * corr + p;
        c0.x = c0.x*corr + p*h0.x;  c0.y = c0.y*corr + p*h0.y;
        c0.z = c0.z*corr + p*h0.z;  c0.w = c0.w*corr + p*h0.w;
        c1.x = c1.x*corr + p*h1.x;  c1.y = c1.y*corr + p*h1.y;
        c1.z = c1.z*corr + p*h1.z;  c1.w = c1.w*corr + p*h1.w;
        m = mn;
    }

    // cross-wave combine in LDS -> one partial per block
    __shared__ float lm[4], ls[4];
    __shared__ float lctx[4][DD];
    lctx[wave][4*lane + 0] = c0.x;  lctx[wave][4*lane + 1] = c0.y;
    lctx[wave][4*lane + 2] = c0.z;  lctx[wave][4*lane + 3] = c0.w;
    lctx[wave][256 + 4*lane + 0] = c1.x;  lctx[wave][256 + 4*lane + 1] = c1.y;
    lctx[wave][256 + 4*lane + 2] = c1.z;  lctx[wave][256 + 4*lane + 3] = c1.w;
    if (lane == 0) { lm[wave] = m; ls[wave] = ssum; }
    __syncthreads();

    const float mb = fmaxf(fmaxf(lm[0], lm[1]), fmaxf(lm[2], lm[3]));
    const float w0 = __expf(lm[0] - mb), w1 = __expf(lm[1] - mb);
    const float w2 = __expf(lm[2] - mb), w3 = __expf(lm[3] - mb);
    const float sb = ls[0]*w0 + ls[1]*w1 + ls[2]*w2 + ls[3]*w3;

    float* p = ws + ((size_t)b * NCHUNK + chunk) * PSTRIDE;
    if (tid == 0) { p[0] = mb; p[1] = sb; }
    p[2 + tid]       = lctx[0][tid]*w0       + lctx[1][tid]*w1       + lctx[2][tid]*w2       + lctx[3][tid]*w3;
    p[2 + 256 + tid] = lctx[0][256+tid]*w0   + lctx[1][256+tid]*w1   + lctx[2][256+tid]*w2   + lctx[3][256+tid]*w3;
}

// ---------------- Pass 2: combine partials -> tanh vector + (m, 1/s) ----------------
__global__ __launch_bounds__(256) void la_pass2(const float* __restrict__ s,
                                                float* __restrict__ ws) {
    const int b = blockIdx.x;
    const int t = threadIdx.x;
    __shared__ float cm[NCHUNK], cs[NCHUNK], cw[NCHUNK];
    const float* pb = ws + (size_t)b * NCHUNK * PSTRIDE;
    if (t < NCHUNK) {
        cm[t] = pb[(size_t)t * PSTRIDE];
        cs[t] = pb[(size_t)t * PSTRIDE + 1];
    }
    __syncthreads();
    float mb = -INFINITY;
    for (int c = 0; c < NCHUNK; ++c) mb = fmaxf(mb, cm[c]);
    float sb = 0.0f;
    for (int c = 0; c < NCHUNK; ++c) sb += cs[c] * __expf(cm[c] - mb);
    if (t < NCHUNK) cw[t] = __expf(cm[t] - mb);
    __syncthreads();
    const float rcp = 1.0f / sb;

    float acc0 = 0.0f, acc1 = 0.0f;
    for (int c = 0; c < NCHUNK; ++c) {
        const float* pc = pb + (size_t)c * PSTRIDE + 2;
        acc0 += cw[c] * pc[t];
        acc1 += cw[c] * pc[t + 256];
    }
    float* tv = ws + TV_OFF + (size_t)b * 1024;
    tv[t]             = tanhf(acc0 * rcp);
    tv[t + 256]       = tanhf(acc1 * rcp);
    tv[512 + t]       = tanhf(s[(size_t)b * DD + t]);
    tv[512 + t + 256] = tanhf(s[(size_t)b * DD + t + 256]);
    if (t == 0) { ws[MS_OFF + 2*b] = mb; ws[MS_OFF + 2*b + 1] = rcp; }
}

// ---------------- Pass 3: normalize scores in-place (a = exp(e-m)/s) ----------------
__global__ __launch_bounds__(256) void la_pass3(float* __restrict__ out,
                                                const float* __restrict__ ws) {
    const int i4 = blockIdx.x * 256 + threadIdx.x;   // B*L/4 = 65536 float4s
    const int b  = i4 >> 11;                         // L/4 = 2048 per batch
    const float mb  = ws[MS_OFF + 2*b];
    const float rcp = ws[MS_OFF + 2*b + 1];
    float4* o4 = (float4*)out;
    float4 e = o4[i4];
    e.x = __expf(e.x - mb) * rcp;
    e.y = __expf(e.y - mb) * rcp;
    e.z = __expf(e.z - mb) * rcp;
    e.w = __expf(e.w - mb) * rcp;
    o4[i4] = e;
}

// ---------------- Pass 4: projection att = tanhvec @ W^T + b (one wave/output) ----------------
__global__ __launch_bounds__(256) void la_pass4(const float* __restrict__ W,
                                                const float* __restrict__ bias,
                                                const float* __restrict__ ws,
                                                float* __restrict__ attOut) {
    const int wv   = blockIdx.x * 4 + (threadIdx.x >> 6);  // global wave id = output id
    const int lane = threadIdx.x & 63;
    const int b = wv >> 9;          // / 512
    const int o = wv & 511;
    const float4* w4 = (const float4*)(W + (size_t)o * 1024);
    const float4* t4 = (const float4*)(ws + TV_OFF + (size_t)b * 1024);
    float acc = 0.0f;
    #pragma unroll
    for (int j = 0; j < 4; ++j) {
        float4 wl = w4[lane + 64*j];
        float4 tl = t4[lane + 64*j];
        acc += wl.x*tl.x + wl.y*tl.y + wl.z*tl.z + wl.w*tl.w;
    }
    #pragma unroll
    for (int off = 32; off > 0; off >>= 1) acc += __shfl_xor(acc, off, 64);
    if (lane == 0) attOut[(size_t)b * DD + o] = acc + bias[o];
}

extern "C" void kernel_launch(void* const* d_in, const int* in_sizes, int n_in,
                              void* d_out, int out_size, void* d_ws, size_t ws_size,
                              hipStream_t stream) {
    const float* h_j    = (const float*)d_in[0];   // [B, L, D]
    const float* s_i    = (const float*)d_in[1];   // [B, 1, D]
    const float* W_proj = (const float*)d_in[2];   // [D, 2D]
    const float* b_proj = (const float*)d_in[3];   // [D]
    float* out = (float*)d_out;                    // [B*L] a  ++  [B*D] att
    float* ws  = (float*)d_ws;

    float* eOut   = out;                           // raw scores -> normalized in pass 3
    float* attOut = out + (size_t)BB * LL;

    la_pass1<<<BB * CHUNKS, 256, 0, stream>>>(h_j, s_i, eOut, ws);
    la_pass2<<<BB, 256, 0, stream>>>(s_i, ws);
    la_pass3<<<(BB * LL / 4) / 256, 256, 0, stream>>>(out, ws);
    la_pass4<<<(BB * DD / 4), 256, 0, stream>>>(W_proj, b_proj, ws, attOut);
}